// Round 1
// baseline (236.772 us; speedup 1.0000x reference)
//
#include <hip/hip_runtime.h>
#include <math.h>

// ConnectedLossV4: argmax -> per-class 4-connected components (min-index labels)
// -> placeholder (exact f32 op-order replication) -> per-target lower median
// (radix select over float bits) -> count-based bce+dice + continuous bg term.
//
// ws layout (N = B*H*W = 1048576):
//   [0,        4N)  parent  int32   (union-find)
//   [4N,       8N)  keys    uint32  (placeholder f32 bit patterns)
//   [8N,       9N)  cls     uint8   (argmax class)
//   [9N, 9N+18KB)   stats   uint32[4608]:
//        [0..7]   cnt_class   [8..15] cnt_target  [16..23] ncomp
//        [24..31] prodf(f32)  [32] presentBits    [33] activeBits
//        [40..47] prefix/med  [48..55] krem(int)
//        [56..63] n11         [64..71] nfm
//        [128..2175] hist[8][256]
//        word 4096: 3 doubles (bg log-sum, inter, sum_pred)

#define HWMASK (262144 - 1)

static __device__ __forceinline__ int ufind(int* p, int x) {
  while (true) {
    int px = p[x];
    if (px == x) return x;
    int g = p[px];
    if (g == px) return px;
    p[x] = g;  // path halving (benign race)
    x = g;
  }
}

static __device__ void unite(int* p, int a, int b) {
  while (true) {
    a = ufind(p, a); b = ufind(p, b);
    if (a == b) return;
    if (a < b) { int old = atomicCAS(&p[b], b, a); if (old == b) return; b = old; }
    else       { int old = atomicCAS(&p[a], a, b); if (old == a) return; a = old; }
  }
}

__global__ void k_init(unsigned* stats) {
  int i = blockIdx.x * blockDim.x + threadIdx.x;
  if (i < 4608) stats[i] = 0u;
}

__global__ void k_argmax(const float* __restrict__ pred, const int* __restrict__ tgt,
                         int* __restrict__ parent, unsigned char* __restrict__ cls,
                         unsigned* __restrict__ stats, int N) {
  __shared__ unsigned hc[8], ht[8];
  if (threadIdx.x < 8) { hc[threadIdx.x] = 0; ht[threadIdx.x] = 0; }
  __syncthreads();
  int stride = gridDim.x * blockDim.x;
  for (int i = blockIdx.x * blockDim.x + threadIdx.x; i < N; i += stride) {
    int b = i >> 18, hw = i & HWMASK;
    const float* pp = pred + ((size_t)b << 21) + hw;
    float best = pp[0]; int c = 0;
#pragma unroll
    for (int ch = 1; ch < 8; ++ch) {        // first-max == numpy argmax
      float v = pp[(size_t)ch << 18];
      if (v > best) { best = v; c = ch; }
    }
    cls[i] = (unsigned char)c;
    parent[i] = i;
    atomicAdd(&hc[c], 1u);
    atomicAdd(&ht[tgt[i] & 7], 1u);
  }
  __syncthreads();
  if (threadIdx.x < 8) {
    if (hc[threadIdx.x]) atomicAdd(&stats[threadIdx.x], hc[threadIdx.x]);
    if (ht[threadIdx.x]) atomicAdd(&stats[8 + threadIdx.x], ht[threadIdx.x]);
  }
}

__global__ void k_merge(const unsigned char* __restrict__ cls, int* __restrict__ parent, int N) {
  int stride = gridDim.x * blockDim.x;
  for (int i = blockIdx.x * blockDim.x + threadIdx.x; i < N; i += stride) {
    int c = cls[i];
    if (!c) continue;
    int hw = i & HWMASK;
    int w = hw & 511, h = hw >> 9;
    if (w < 511 && cls[i + 1] == c)   unite(parent, i, i + 1);
    if (h < 511 && cls[i + 512] == c) unite(parent, i, i + 512);
  }
}

__global__ void k_flatten(const unsigned char* __restrict__ cls, int* __restrict__ parent,
                          unsigned* __restrict__ stats, int N) {
  __shared__ unsigned nc[8];
  if (threadIdx.x < 8) nc[threadIdx.x] = 0;
  __syncthreads();
  int stride = gridDim.x * blockDim.x;
  for (int i = blockIdx.x * blockDim.x + threadIdx.x; i < N; i += stride) {
    int c = cls[i];
    if (!c) continue;
    int r = ufind(parent, i);
    parent[i] = r;
    if (r == i) atomicAdd(&nc[c], 1u);   // component representative (min idx)
  }
  __syncthreads();
  if (threadIdx.x < 8 && nc[threadIdx.x]) atomicAdd(&stats[16 + threadIdx.x], nc[threadIdx.x]);
}

__global__ void k_scalars(unsigned* stats, int N) {
  if (blockIdx.x | threadIdx.x) return;
  float* prodf = (float*)(stats + 24);
  int last_i = 1;
  unsigned pb = 0;
  for (int v = 1; v < 8; ++v) {
    unsigned cntv = stats[v], ncv = stats[16 + v];
    if (cntv) {
      prodf[v] = __fmul_rn((float)ncv, (float)last_i);  // exact ref rounding
      pb |= 1u << v;
      last_i += (int)ncv + ((cntv < (unsigned)N) ? 1 : 0);  // + has_bg
    } else prodf[v] = 0.0f;
  }
  stats[32] = pb;
  unsigned ab = 0;
  for (int t = 1; t < 8; ++t) {
    unsigned n = stats[8 + t];
    ((int*)stats)[48 + t] = n ? (int)((n - 1) >> 1) : -1;  // lower-median rank
    stats[40 + t] = 0;
    if (n) ab |= 1u << t;
  }
  stats[33] = ab;
}

__global__ void k_placeholder(const unsigned char* __restrict__ cls, const int* __restrict__ parent,
                              const unsigned* __restrict__ stats, unsigned* __restrict__ keys, int N) {
  __shared__ float sprod[8];
  __shared__ unsigned spb;
  if (threadIdx.x < 8) sprod[threadIdx.x] = ((const float*)(stats + 24))[threadIdx.x];
  if (threadIdx.x == 0) spb = stats[32];
  __syncthreads();
  unsigned pb = spb;
  int stride = gridDim.x * blockDim.x;
  for (int i = blockIdx.x * blockDim.x + threadIdx.x; i < N; i += stride) {
    int c = cls[i];
    float lab = 0.0f;
    if (c) lab = (float)(parent[i] + 1);   // < 2^24, exact
    float ph = 0.0f;
#pragma unroll
    for (int v = 1; v < 8; ++v) {          // exact numpy op order: ((lab+prod) then +=)
      if (pb & (1u << v)) {
        float term = sprod[v];
        if (c == v) term = __fadd_rn(lab, term);
        ph = __fadd_rn(ph, term);
      }
    }
    keys[i] = __float_as_uint(ph);         // ph >= 0 -> uint order == float order
  }
}

__global__ void k_hist(const unsigned* __restrict__ keys, const int* __restrict__ tgt,
                       unsigned* __restrict__ stats, int b, int N) {
  __shared__ unsigned lh[2048];
  __shared__ unsigned spre[8];
  __shared__ unsigned sab;
  for (int j = threadIdx.x; j < 2048; j += blockDim.x) lh[j] = 0;
  if (threadIdx.x < 8) spre[threadIdx.x] = stats[40 + threadIdx.x];
  if (threadIdx.x == 0) sab = stats[33];
  __syncthreads();
  unsigned ab = sab;
  int shift = 8 * b;
  unsigned maskhi = (b == 3) ? 0u : (0xFFFFFFFFu << (shift + 8));
  int stride = gridDim.x * blockDim.x;
  for (int i = blockIdx.x * blockDim.x + threadIdx.x; i < N; i += stride) {
    int t = tgt[i] & 7;
    if (t && (ab >> t & 1u)) {
      unsigned key = keys[i];
      if (((key ^ spre[t]) & maskhi) == 0u)
        atomicAdd(&lh[(t << 8) | ((key >> shift) & 255u)], 1u);
    }
  }
  __syncthreads();
  for (int j = threadIdx.x; j < 2048; j += blockDim.x) {
    unsigned v = lh[j];
    if (v) atomicAdd(&stats[128 + j], v);
  }
}

__global__ void k_scan(unsigned* stats, int b) {
  int t = threadIdx.x;
  if (t >= 1 && t < 8 && (stats[33] >> t & 1u)) {
    int k = ((int*)stats)[48 + t];
    int shift = 8 * b;
    unsigned cum = 0;
    for (int bin = 0; bin < 256; ++bin) {
      unsigned c = stats[128 + (t << 8) + bin];
      if (cum + c > (unsigned)k) {
        stats[40 + t] |= ((unsigned)bin) << shift;
        ((int*)stats)[48 + t] = k - (int)cum;
        break;
      }
      cum += c;
    }
  }
  __syncthreads();
  for (int j = threadIdx.x; j < 2048; j += blockDim.x) stats[128 + j] = 0;  // next pass
}

__global__ void k_final(const float* __restrict__ pred, const int* __restrict__ tgt,
                        const unsigned char* __restrict__ cls, const unsigned* __restrict__ keys,
                        unsigned* __restrict__ stats, double* __restrict__ dsum, int N) {
  __shared__ unsigned s11[8], sfm[8], smed[8];
  __shared__ unsigned sab;
  __shared__ double red[256];
  if (threadIdx.x < 8) { s11[threadIdx.x] = 0; sfm[threadIdx.x] = 0; smed[threadIdx.x] = stats[40 + threadIdx.x]; }
  if (threadIdx.x == 0) sab = stats[33];
  __syncthreads();
  unsigned ab = sab;
  double accL = 0.0, accI = 0.0, accP = 0.0;
  int stride = gridDim.x * blockDim.x;
  for (int i = blockIdx.x * blockDim.x + threadIdx.x; i < N; i += stride) {
    unsigned kb = keys[i];
    int t = tgt[i] & 7;
#pragma unroll
    for (int tt = 1; tt < 8; ++tt) {
      if ((ab >> tt & 1u) && kb == smed[tt]) {
        atomicAdd(&sfm[tt], 1u);
        if (t == tt) atomicAdd(&s11[tt], 1u);
      }
    }
    // background term (continuous)
    int b = i >> 18, hw = i & HWMASK;
    float p0 = pred[((size_t)b << 21) + hw];      // channel 0
    float pv = (cls[i] == 0) ? p0 : 0.0f;
    float pc = fminf(fmaxf(pv, 1e-7f), 1.0f - 1e-7f);
    if (t == 0) { accL += log((double)pc); accI += (double)pv; }
    else        { accL += log((double)(1.0f - pc)); }  // f32 subtract like ref
    accP += (double)pv;
  }
#pragma unroll
  for (int pass = 0; pass < 3; ++pass) {
    double v = (pass == 0) ? accL : ((pass == 1) ? accI : accP);
    red[threadIdx.x] = v; __syncthreads();
    for (int s = 128; s > 0; s >>= 1) {
      if (threadIdx.x < s) red[threadIdx.x] += red[threadIdx.x + s];
      __syncthreads();
    }
    if (threadIdx.x == 0) atomicAdd(&dsum[pass], red[0]);
    __syncthreads();
  }
  if (threadIdx.x < 8) {
    if (sfm[threadIdx.x]) atomicAdd(&stats[64 + threadIdx.x], sfm[threadIdx.x]);
    if (s11[threadIdx.x]) atomicAdd(&stats[56 + threadIdx.x], s11[threadIdx.x]);
  }
}

__global__ void k_finalize(const unsigned* __restrict__ stats, const double* __restrict__ dsum,
                           float* __restrict__ out, int N) {
  if (blockIdx.x | threadIdx.x) return;
  double Nd = (double)N;
  double res = -dsum[0] / Nd;  // bce_bg
  res += 1.0 - (2.0 * dsum[1] + 1.0) / (dsum[2] + (double)stats[8] + 1.0);  // dice_bg
  const float e32 = 1e-7f;
  const float c1 = 1.0f - e32;           // clip upper (f32)
  const float omc1 = 1.0f - c1;          // = 2^-23 (f32)
  double lp1 = log((double)c1);          // t=1, fm=1
  double lp0 = log((double)e32);         // t=1, fm=0
  double l01 = log((double)omc1);        // t=0, fm=1
  double l00 = lp1;                      // t=0, fm=0 : log(1-eps)=log(c1)
  unsigned ab = stats[33];
  for (int t = 1; t < 8; ++t) {
    if (ab >> t & 1u) {
      double a = (double)stats[56 + t];  // n11
      double f = (double)stats[64 + t];  // |full_med|
      double n = (double)stats[8 + t];   // |tm|
      double bce = -(a * lp1 + (n - a) * lp0 + (f - a) * l01 + (Nd - n - f + a) * l00) / Nd;
      double dice = 1.0 - (2.0 * a + 1.0) / (f + n + 1.0);
      res += bce + dice;
    }
  }
  int nu = 0;
  for (int t = 0; t < 8; ++t) nu += (stats[8 + t] > 0);
  out[0] = (float)(res / ((double)nu + 1.0));
}

extern "C" void kernel_launch(void* const* d_in, const int* in_sizes, int n_in,
                              void* d_out, int out_size, void* d_ws, size_t ws_size,
                              hipStream_t stream) {
  const float* pred = (const float*)d_in[0];   // [B,8,512,512] f32
  const int* tgt = (const int*)d_in[1];        // [B,1,512,512] i32
  int N = in_sizes[1];                         // B*H*W
  char* ws = (char*)d_ws;
  int* parent = (int*)ws;
  unsigned* keys = (unsigned*)(ws + (size_t)N * 4);
  unsigned char* cls = (unsigned char*)(ws + (size_t)N * 8);
  unsigned* stats = (unsigned*)(ws + (size_t)N * 9);
  double* dsum = (double*)(ws + (size_t)N * 9 + 16384);
  float* out = (float*)d_out;

  dim3 tb(256);
  int nblk = 1024;
  k_init<<<18, tb, 0, stream>>>(stats);
  k_argmax<<<nblk, tb, 0, stream>>>(pred, tgt, parent, cls, stats, N);
  k_merge<<<nblk, tb, 0, stream>>>(cls, parent, N);
  k_flatten<<<nblk, tb, 0, stream>>>(cls, parent, stats, N);
  k_scalars<<<1, 1, 0, stream>>>(stats, N);
  k_placeholder<<<nblk, tb, 0, stream>>>(cls, parent, stats, keys, N);
  for (int b = 3; b >= 0; --b) {
    k_hist<<<nblk, tb, 0, stream>>>(keys, tgt, stats, b, N);
    k_scan<<<1, tb, 0, stream>>>(stats, b);
  }
  k_final<<<nblk, tb, 0, stream>>>(pred, tgt, cls, keys, stats, dsum, N);
  k_finalize<<<1, 1, 0, stream>>>(stats, dsum, out, N);
}

// Round 2
// 208.806 us; speedup vs baseline: 1.1339x; 1.1339x over previous
//
#include <hip/hip_runtime.h>
#include <math.h>

// ConnectedLossV4: argmax -> per-class 4-connected components (min-index labels)
// -> placeholder (exact f32 op-order replication) -> per-target lower median
// (3-pass 11/11/10-bit radix select over float bits) -> count-based bce+dice.
// Continuous bg term fused into argmax (only cls==0 pixels need a real log).
//
// ws layout (N = B*H*W = 1048576):
//   [0,   4N)  parent int32 (union-find; reused as radix hist[7][2048] after placeholder)
//   [4N,  8N)  keys   uint32 (placeholder f32 bit patterns)
//   [8N,  9N)  pk     uint8  (cls | tgt<<3)
//   [9N, ...)  stats  uint32[4608]:
//     [0..7] cnt_class [8..15] cnt_target [16..23] ncomp [24..31] prodf(f32)
//     [32] presentBits [33] activeBits [34] n(c!=0,t==0) [35] n(c!=0,t!=0)
//     [40..47] median prefix [48..55] krem [56..63] n11 [64..71] nfm
//     words 96..287: double dsl[3][32] (bg logsum / inter / sum_pred slots)

#define HWMASK (262144 - 1)

static __device__ __forceinline__ int ufind(int* p, int x) {
  while (true) {
    int px = p[x];
    if (px == x) return x;
    int g = p[px];
    if (g == px) return px;
    p[x] = g;  // path halving (benign race)
    x = g;
  }
}

static __device__ void unite(int* p, int a, int b) {
  while (true) {
    a = ufind(p, a); b = ufind(p, b);
    if (a == b) return;
    if (a < b) { int old = atomicCAS(&p[b], b, a); if (old == b) return; b = old; }
    else       { int old = atomicCAS(&p[a], a, b); if (old == a) return; a = old; }
  }
}

__global__ void k_argmax(const float* __restrict__ pred, const int* __restrict__ tgt,
                         int* __restrict__ parent, unsigned char* __restrict__ pk,
                         unsigned* __restrict__ stats, int N) {
  __shared__ unsigned hc[8], ht[8], hA, hB;
  __shared__ double dred[12];
  int tid = threadIdx.x;
  if (tid < 8) { hc[tid] = 0; ht[tid] = 0; }
  if (tid == 0) { hA = 0; hB = 0; }
  __syncthreads();
  int n4 = N >> 2;
  int stride = gridDim.x * blockDim.x;
  double aL = 0.0, aI = 0.0, aP = 0.0;
  unsigned nA = 0, nB = 0;
  for (int i4 = blockIdx.x * blockDim.x + tid; i4 < n4; i4 += stride) {
    int i = i4 << 2;
    int b = i >> 18, hw = i & HWMASK;
    const float* pp = pred + ((size_t)b << 21) + hw;
    float4 v[8];
#pragma unroll
    for (int ch = 0; ch < 8; ++ch) v[ch] = *(const float4*)(pp + ((size_t)ch << 18));
    int4 tv = *(const int4*)(tgt + i);
    int tarr[4] = {tv.x & 7, tv.y & 7, tv.z & 7, tv.w & 7};
    unsigned char pkb[4];
#pragma unroll
    for (int j = 0; j < 4; ++j) {
      float p0 = ((const float*)&v[0])[j];
      float best = p0; int c = 0;
#pragma unroll
      for (int ch = 1; ch < 8; ++ch) {           // first-max == numpy argmax
        float x = ((const float*)&v[ch])[j];
        if (x > best) { best = x; c = ch; }
      }
      int t = tarr[j];
      pkb[j] = (unsigned char)(c | (t << 3));
      atomicAdd(&hc[c], 1u);
      atomicAdd(&ht[t], 1u);
      if (c == 0) {                              // continuous bg term
        float pc = fminf(fmaxf(p0, 1e-7f), 1.0f - 1e-7f);
        if (t == 0) { aL += (double)logf(pc); aI += (double)p0; }
        else        { aL += (double)logf(1.0f - pc); }
        aP += (double)p0;
      } else {                                   // pv==0 -> constant log, just count
        if (t == 0) nA++; else nB++;
      }
    }
    *(int4*)(parent + i) = make_int4(i, i + 1, i + 2, i + 3);
    *(uchar4*)(pk + i) = make_uchar4(pkb[0], pkb[1], pkb[2], pkb[3]);
  }
  if (nA) atomicAdd(&hA, nA);
  if (nB) atomicAdd(&hB, nB);
#pragma unroll
  for (int o = 32; o > 0; o >>= 1) {
    aL += __shfl_down(aL, o); aI += __shfl_down(aI, o); aP += __shfl_down(aP, o);
  }
  int wid = tid >> 6, lane = tid & 63;
  if (lane == 0) { dred[wid] = aL; dred[4 + wid] = aI; dred[8 + wid] = aP; }
  __syncthreads();
  if (tid == 0) {
    double L = dred[0] + dred[1] + dred[2] + dred[3];
    double I = dred[4] + dred[5] + dred[6] + dred[7];
    double P = dred[8] + dred[9] + dred[10] + dred[11];
    double* dsl = (double*)(stats + 96);
    int s = blockIdx.x & 31;
    atomicAdd(&dsl[s], L); atomicAdd(&dsl[32 + s], I); atomicAdd(&dsl[64 + s], P);
    if (hA) atomicAdd(&stats[34], hA);
    if (hB) atomicAdd(&stats[35], hB);
  }
  if (tid < 8) {
    if (hc[tid]) atomicAdd(&stats[tid], hc[tid]);
    if (ht[tid]) atomicAdd(&stats[8 + tid], ht[tid]);
  }
}

__global__ void k_merge(const unsigned char* __restrict__ pk, int* __restrict__ parent, int N) {
  int stride = gridDim.x * blockDim.x;
  for (int i = blockIdx.x * blockDim.x + threadIdx.x; i < N; i += stride) {
    int c = pk[i] & 7;
    if (!c) continue;
    int hw = i & HWMASK;
    int w = hw & 511, h = hw >> 9;
    if (w < 511 && (pk[i + 1] & 7) == c)   unite(parent, i, i + 1);
    if (h < 511 && (pk[i + 512] & 7) == c) unite(parent, i, i + 512);
  }
}

__global__ void k_flatten(const unsigned char* __restrict__ pk, int* __restrict__ parent,
                          unsigned* __restrict__ stats, int N) {
  __shared__ unsigned nc[8];
  if (threadIdx.x < 8) nc[threadIdx.x] = 0;
  __syncthreads();
  int stride = gridDim.x * blockDim.x;
  for (int i = blockIdx.x * blockDim.x + threadIdx.x; i < N; i += stride) {
    int c = pk[i] & 7;
    if (!c) continue;
    int r = ufind(parent, i);
    parent[i] = r;
    if (r == i) atomicAdd(&nc[c], 1u);   // component representative (min idx)
  }
  __syncthreads();
  if (threadIdx.x < 8 && nc[threadIdx.x]) atomicAdd(&stats[16 + threadIdx.x], nc[threadIdx.x]);
}

__global__ void k_scalars(unsigned* stats, int N) {
  if (blockIdx.x | threadIdx.x) return;
  float* prodf = (float*)(stats + 24);
  int last_i = 1;
  unsigned pb = 0;
  for (int v = 1; v < 8; ++v) {
    unsigned cntv = stats[v], ncv = stats[16 + v];
    if (cntv) {
      prodf[v] = __fmul_rn((float)ncv, (float)last_i);  // exact ref rounding
      pb |= 1u << v;
      last_i += (int)ncv + ((cntv < (unsigned)N) ? 1 : 0);  // + has_bg
    } else prodf[v] = 0.0f;
  }
  stats[32] = pb;
  unsigned ab = 0;
  for (int t = 1; t < 8; ++t) {
    unsigned n = stats[8 + t];
    ((int*)stats)[48 + t] = n ? (int)((n - 1) >> 1) : -1;  // lower-median rank
    if (n) ab |= 1u << t;
  }
  stats[33] = ab;
}

__global__ void k_placeholder(const unsigned char* __restrict__ pk, const int* __restrict__ parent,
                              const unsigned* __restrict__ stats, unsigned* __restrict__ keys, int N) {
  __shared__ float sprod[8];
  __shared__ unsigned spb;
  if (threadIdx.x < 8) sprod[threadIdx.x] = ((const float*)(stats + 24))[threadIdx.x];
  if (threadIdx.x == 0) spb = stats[32];
  __syncthreads();
  unsigned pb = spb;
  int n4 = N >> 2;
  int stride = gridDim.x * blockDim.x;
  for (int i4 = blockIdx.x * blockDim.x + threadIdx.x; i4 < n4; i4 += stride) {
    int i = i4 << 2;
    int4 pr = *(const int4*)(parent + i);
    uchar4 pv = *(const uchar4*)(pk + i);
    int parr[4] = {pr.x, pr.y, pr.z, pr.w};
    int carr[4] = {pv.x & 7, pv.y & 7, pv.z & 7, pv.w & 7};
    unsigned ko[4];
#pragma unroll
    for (int j = 0; j < 4; ++j) {
      int c = carr[j];
      float lab = c ? (float)(parr[j] + 1) : 0.0f;   // < 2^24, exact
      float ph = 0.0f;
#pragma unroll
      for (int v = 1; v < 8; ++v) {                  // exact numpy op order
        if (pb & (1u << v)) {
          float term = sprod[v];
          if (c == v) term = __fadd_rn(lab, term);
          ph = __fadd_rn(ph, term);
        }
      }
      ko[j] = __float_as_uint(ph);                   // ph >= 0 -> uint order == float order
    }
    *(uint4*)(keys + i) = make_uint4(ko[0], ko[1], ko[2], ko[3]);
  }
}

__global__ void k_hist(const unsigned* __restrict__ keys, const unsigned char* __restrict__ pk,
                       const unsigned* __restrict__ stats, unsigned* __restrict__ hist,
                       int shift, unsigned bmask, unsigned maskhi, int N) {
  __shared__ unsigned lh[14336];      // 7 targets x 2048 bins
  __shared__ unsigned spre[8];
  __shared__ unsigned sab;
  for (int j = threadIdx.x; j < 14336; j += blockDim.x) lh[j] = 0;
  if (threadIdx.x < 8) spre[threadIdx.x] = stats[40 + threadIdx.x];
  if (threadIdx.x == 0) sab = stats[33];
  __syncthreads();
  unsigned ab = sab;
  int n4 = N >> 2;
  int stride = gridDim.x * blockDim.x;
  for (int i4 = blockIdx.x * blockDim.x + threadIdx.x; i4 < n4; i4 += stride) {
    int i = i4 << 2;
    uint4 kv = *(const uint4*)(keys + i);
    uchar4 pv = *(const uchar4*)(pk + i);
    unsigned karr[4] = {kv.x, kv.y, kv.z, kv.w};
    int tarr[4] = {pv.x >> 3, pv.y >> 3, pv.z >> 3, pv.w >> 3};
#pragma unroll
    for (int j = 0; j < 4; ++j) {
      int t = tarr[j];
      if (t && (ab >> t & 1u)) {
        unsigned key = karr[j];
        if (((key ^ spre[t]) & maskhi) == 0u)
          atomicAdd(&lh[((t - 1) << 11) | ((key >> shift) & bmask)], 1u);
      }
    }
  }
  __syncthreads();
  for (int j = threadIdx.x; j < 14336; j += blockDim.x) {
    unsigned v = lh[j];
    if (v) atomicAdd(&hist[j], v);
  }
}

__global__ void k_scan(unsigned* __restrict__ stats, unsigned* __restrict__ hist,
                       int shift, int nb, int doclear) {
  __shared__ unsigned part[256];
  int tid = threadIdx.x;
  int per = nb >> 8;
  unsigned ab = stats[33];
  for (int t = 1; t < 8; ++t) {
    if (!(ab >> t & 1u)) continue;
    int k = ((int*)stats)[48 + t];
    unsigned* h = hist + ((t - 1) << 11);
    int base = tid * per;
    unsigned s = 0;
    for (int j = 0; j < per; ++j) s += h[base + j];
    part[tid] = s;
    __syncthreads();
    for (int off = 1; off < 256; off <<= 1) {       // inclusive Hillis-Steele
      unsigned v = (tid >= off) ? part[tid - off] : 0u;
      __syncthreads();
      part[tid] += v;
      __syncthreads();
    }
    unsigned incl = part[tid];
    unsigned excl = incl - s;
    if ((unsigned)k >= excl && (unsigned)k < incl) { // unique owner walks its chunk
      unsigned cum = excl;
      for (int j = 0; j < per; ++j) {
        unsigned c = h[base + j];
        if (cum + c > (unsigned)k) {
          stats[40 + t] |= ((unsigned)(base + j)) << shift;
          ((int*)stats)[48 + t] = k - (int)cum;
          break;
        }
        cum += c;
      }
    }
    __syncthreads();
  }
  if (doclear)
    for (int j = tid; j < 14336; j += blockDim.x) hist[j] = 0;
}

__global__ void k_medcount(const unsigned* __restrict__ keys, const unsigned char* __restrict__ pk,
                           unsigned* __restrict__ stats, int N) {
  __shared__ unsigned s11[8], sfm[8], smed[8];
  __shared__ unsigned sab;
  if (threadIdx.x < 8) { s11[threadIdx.x] = 0; sfm[threadIdx.x] = 0; smed[threadIdx.x] = stats[40 + threadIdx.x]; }
  if (threadIdx.x == 0) sab = stats[33];
  __syncthreads();
  unsigned ab = sab;
  int n4 = N >> 2;
  int stride = gridDim.x * blockDim.x;
  for (int i4 = blockIdx.x * blockDim.x + threadIdx.x; i4 < n4; i4 += stride) {
    int i = i4 << 2;
    uint4 kv = *(const uint4*)(keys + i);
    uchar4 pv = *(const uchar4*)(pk + i);
    unsigned karr[4] = {kv.x, kv.y, kv.z, kv.w};
    int tarr[4] = {pv.x >> 3, pv.y >> 3, pv.z >> 3, pv.w >> 3};
#pragma unroll
    for (int j = 0; j < 4; ++j) {
      unsigned kb = karr[j];
      int t = tarr[j];
#pragma unroll
      for (int tt = 1; tt < 8; ++tt) {
        if ((ab >> tt & 1u) && kb == smed[tt]) {
          atomicAdd(&sfm[tt], 1u);
          if (t == tt) atomicAdd(&s11[tt], 1u);
        }
      }
    }
  }
  __syncthreads();
  if (threadIdx.x < 8) {
    if (sfm[threadIdx.x]) atomicAdd(&stats[64 + threadIdx.x], sfm[threadIdx.x]);
    if (s11[threadIdx.x]) atomicAdd(&stats[56 + threadIdx.x], s11[threadIdx.x]);
  }
}

__global__ void k_finalize(const unsigned* __restrict__ stats, float* __restrict__ out, int N) {
  int tid = threadIdx.x;
  const double* dsl = (const double*)(stats + 96);
  double vL = 0.0, vI = 0.0, vP = 0.0;
  if (tid < 32) { vL = dsl[tid]; vI = dsl[32 + tid]; vP = dsl[64 + tid]; }
#pragma unroll
  for (int o = 32; o > 0; o >>= 1) {
    vL += __shfl_down(vL, o); vI += __shfl_down(vI, o); vP += __shfl_down(vP, o);
  }
  if (tid) return;
  double Nd = (double)N;
  const float e32 = 1e-7f;
  const float c1 = 1.0f - e32;           // clip upper (f32)
  const float omc1 = 1.0f - c1;
  double lp1 = log((double)c1);
  double lp0 = log((double)e32);
  double l01 = log((double)omc1);
  double l00 = lp1;
  // bg: add constant-log contributions for cls!=0 pixels
  double L = vL + (double)stats[34] * lp0 + (double)stats[35] * l00;
  double res = -L / Nd;                                                   // bce_bg
  res += 1.0 - (2.0 * vI + 1.0) / (vP + (double)stats[8] + 1.0);          // dice_bg
  unsigned ab = stats[33];
  for (int t = 1; t < 8; ++t) {
    if (ab >> t & 1u) {
      double a = (double)stats[56 + t];  // n11
      double f = (double)stats[64 + t];  // |full_med|
      double n = (double)stats[8 + t];   // |tm|
      double bce = -(a * lp1 + (n - a) * lp0 + (f - a) * l01 + (Nd - n - f + a) * l00) / Nd;
      double dice = 1.0 - (2.0 * a + 1.0) / (f + n + 1.0);
      res += bce + dice;
    }
  }
  int nu = 0;
  for (int t = 0; t < 8; ++t) nu += (stats[8 + t] > 0);
  out[0] = (float)(res / ((double)nu + 1.0));
}

extern "C" void kernel_launch(void* const* d_in, const int* in_sizes, int n_in,
                              void* d_out, int out_size, void* d_ws, size_t ws_size,
                              hipStream_t stream) {
  const float* pred = (const float*)d_in[0];   // [B,8,512,512] f32
  const int* tgt = (const int*)d_in[1];        // [B,1,512,512] i32
  int N = in_sizes[1];                         // B*H*W
  char* ws = (char*)d_ws;
  int* parent = (int*)ws;
  unsigned* keys = (unsigned*)(ws + (size_t)N * 4);
  unsigned char* pk = (unsigned char*)(ws + (size_t)N * 8);
  unsigned* stats = (unsigned*)(ws + (size_t)N * 9);
  unsigned* hist = (unsigned*)parent;          // reused after k_placeholder
  float* out = (float*)d_out;

  dim3 tb(256);
  hipMemsetAsync(stats, 0, 4608 * 4, stream);
  k_argmax<<<1024, tb, 0, stream>>>(pred, tgt, parent, pk, stats, N);
  k_merge<<<2048, tb, 0, stream>>>(pk, parent, N);
  k_flatten<<<2048, tb, 0, stream>>>(pk, parent, stats, N);
  k_scalars<<<1, 1, 0, stream>>>(stats, N);
  k_placeholder<<<1024, tb, 0, stream>>>(pk, parent, stats, keys, N);
  hipMemsetAsync(hist, 0, 14336 * 4, stream);
  // radix select: bits [31:21], [20:10], [9:0]
  k_hist<<<1024, tb, 0, stream>>>(keys, pk, stats, hist, 21, 2047u, 0u, N);
  k_scan<<<1, tb, 0, stream>>>(stats, hist, 21, 2048, 1);
  k_hist<<<1024, tb, 0, stream>>>(keys, pk, stats, hist, 10, 2047u, 0xFFE00000u, N);
  k_scan<<<1, tb, 0, stream>>>(stats, hist, 10, 2048, 1);
  k_hist<<<1024, tb, 0, stream>>>(keys, pk, stats, hist, 0, 1023u, 0xFFFFFC00u, N);
  k_scan<<<1, tb, 0, stream>>>(stats, hist, 0, 1024, 0);
  k_medcount<<<1024, tb, 0, stream>>>(keys, pk, stats, N);
  k_finalize<<<1, 64, 0, stream>>>(stats, out, N);
}